// Round 4
// baseline (50.237 us; speedup 1.0000x reference)
//
#include <hip/hip_runtime.h>

#define BATCH 4
#define NPTS 4096
#define NT 256               // NPTS/16 tiles
#define SCONST 0.72134752f   // 0.5*log2(e)

typedef __attribute__((ext_vector_type(8))) short short8;
typedef __attribute__((ext_vector_type(4))) float f32x4;
typedef unsigned int uint32;
typedef unsigned short ushort16;

__device__ __forceinline__ unsigned short bf16rn(float x) {
    uint32 u = __float_as_uint(x);
    uint32 r = (u + 0x7FFFu + ((u >> 16) & 1u)) >> 16;
    return (unsigned short)r;
}
__device__ __forceinline__ float bf16tof(unsigned short h) {
    return __uint_as_float(((uint32)h) << 16);
}
// orderable float<->uint for atomicMin
__device__ __forceinline__ uint32 fenc(float f) {
    uint32 u = __float_as_uint(f);
    return (u & 0x80000000u) ? ~u : (u | 0x80000000u);
}
__device__ __forceinline__ float fdec(uint32 u) {
    return __uint_as_float((u & 0x80000000u) ? (u & 0x7FFFFFFFu) : ~u);
}

// K-slot patterns (9 of 32 used): A (cloud) = [ch3, cl3, ch3, 0...]
//                                 B (query) = [qh3, qh3, ql3, 0...]
// dot = ch.qh + cl.qh + ch.ql ~= c.q  (missing cl.ql ~ 2^-18)
__device__ __forceinline__ short8 make_fragA(int kb, unsigned short hx, unsigned short hy,
        unsigned short hz, unsigned short lx, unsigned short ly, unsigned short lz) {
    short8 f = (short8)0;
    if (kb == 0) { f[0]=hx; f[1]=hy; f[2]=hz; f[3]=lx; f[4]=ly; f[5]=lz; f[6]=hx; f[7]=hy; }
    else if (kb == 1) { f[0]=hz; }
    return f;
}
__device__ __forceinline__ short8 make_fragB(int kb, unsigned short hx, unsigned short hy,
        unsigned short hz, unsigned short lx, unsigned short ly, unsigned short lz) {
    short8 f = (short8)0;
    if (kb == 0) { f[0]=hx; f[1]=hy; f[2]=hz; f[3]=hx; f[4]=hy; f[5]=hz; f[6]=lx; f[7]=ly; }
    else if (kb == 1) { f[0]=lz; }
    return f;
}

// ---- pack: build A-fragments (cloud side, raw split) + norm arrays + inits ----
// kinds: 0=pc1, 1=pc2, 2=pc1w. Apack[kind][b][tile][lane] (16B each).
__global__ __launch_bounds__(256) void pack_kernel(
    const float* __restrict__ pc1, const float* __restrict__ pc2,
    const float* __restrict__ pc1w,
    short8* __restrict__ Apack, float* __restrict__ c0_1, float* __restrict__ c0_2,
    float* __restrict__ h0_2, float* __restrict__ h0_w,
    float* __restrict__ dsum, uint32* __restrict__ dmin_u, float* __restrict__ out)
{
    const int gid = blockIdx.x * 256 + threadIdx.x;   // 3*4*256*64 = 196608
    // inits (main kernel runs in a later dispatch -> ordered)
    if (gid == 0) out[0] = 0.0f;
    if (gid < 2 * BATCH * NPTS) dsum[gid] = 0.0f;
    else if (gid < 4 * BATCH * NPTS) dmin_u[gid - 2 * BATCH * NPTS] = 0xFFFFFFFFu;

    const int kind = gid >> 16;
    const int r    = gid & 65535;
    const int b    = r >> 14;
    const int t    = (r >> 6) & 255;
    const int l    = r & 63;
    const int col  = l & 15, kb = l >> 4;
    const int p    = t * 16 + col;

    const float* src = (kind == 0) ? pc1 : (kind == 1) ? pc2 : pc1w;
    const size_t base = (size_t)b * 3 * NPTS;
    const float x = src[base + p], y = src[base + NPTS + p], z = src[base + 2 * NPTS + p];

    const unsigned short hx = bf16rn(x), hy = bf16rn(y), hz = bf16rn(z);
    const unsigned short lx = bf16rn(x - bf16tof(hx)),
                         ly = bf16rn(y - bf16tof(hy)),
                         lz = bf16rn(z - bf16tof(hz));
    Apack[gid] = make_fragA(kb, hx, hy, hz, lx, ly, lz);

    if (kb == 0) {
        const float n2 = x * x + y * y + z * z;
        const int o = b * NPTS + p;
        if (kind == 0) c0_1[o] = -SCONST * n2;
        else if (kind == 1) { c0_2[o] = -SCONST * n2; h0_2[o] = n2; }
        else h0_w[o] = n2;
    }
}

// ---- main: MFMA cross-products, per-tile epilogue, ws combine ----
__global__ __launch_bounds__(256) void chamfer_mfma(
    const float* __restrict__ pc1, const float* __restrict__ pc2,
    const float* __restrict__ pc1w, const short8* __restrict__ Apack,
    const float* __restrict__ c0_1, const float* __restrict__ c0_2,
    const float* __restrict__ h0_2, const float* __restrict__ h0_w,
    float* __restrict__ dsum, uint32* __restrict__ dmin_u)
{
    const int blk  = blockIdx.x;
    const int dirb = blk & 7;            // 8 combos -> 8 XCDs (L2 affinity)
    const int dir  = dirb >> 2, b = dirb & 3;
    const int rest = blk >> 3;           // 0..127
    const int qb   = rest & 31;          // 32 query-blocks of 128
    const int jc   = rest >> 5;          // 4 cloud chunks of 64 tiles
    const int tid  = threadIdx.x, l = tid & 63, w = tid >> 6;
    const int col  = l & 15, kb = l >> 4;

    // this wave's two query tiles
    const int qt0 = qb * 8 + w * 2;
    const int q0i = qt0 * 16 + col, q1i = q0i + 16;

    // query sources; scales baked into B: dens *= 2s, dist *= -2
    const float* qdens = dir ? pc2 : pc1;
    const float* qdist = dir ? pc2 : pc1w;
    const size_t qbase = (size_t)b * 3 * NPTS;

    short8 Bd0, Bd1, Bt0, Bt1;
    {
        const float s2 = 2.0f * SCONST;
        #pragma unroll
        for (int qt = 0; qt < 2; ++qt) {
            const int qi = qt ? q1i : q0i;
            float dx = qdens[qbase + qi] * s2, dy = qdens[qbase + NPTS + qi] * s2,
                  dz = qdens[qbase + 2 * NPTS + qi] * s2;
            float tx = qdist[qbase + qi] * -2.0f, ty = qdist[qbase + NPTS + qi] * -2.0f,
                  tz = qdist[qbase + 2 * NPTS + qi] * -2.0f;
            unsigned short dhx = bf16rn(dx), dhy = bf16rn(dy), dhz = bf16rn(dz);
            unsigned short dlx = bf16rn(dx - bf16tof(dhx)), dly = bf16rn(dy - bf16tof(dhy)),
                           dlz = bf16rn(dz - bf16tof(dhz));
            unsigned short thx = bf16rn(tx), thy = bf16rn(ty), thz = bf16rn(tz);
            unsigned short tlx = bf16rn(tx - bf16tof(thx)), tly = bf16rn(ty - bf16tof(thy)),
                           tlz = bf16rn(tz - bf16tof(thz));
            short8 bd = make_fragB(kb, dhx, dhy, dhz, dlx, dly, dlz);
            short8 bt = make_fragB(kb, thx, thy, thz, tlx, tly, tlz);
            if (qt == 0) { Bd0 = bd; Bt0 = bt; } else { Bd1 = bd; Bt1 = bt; }
        }
    }

    // cloud A-streams: dir0 both = pc2(kind1); dir1 dens = pc1(kind0), dist = pc1w(kind2)
    const int kindD = dir ? 0 : 1;
    const int kindT = dir ? 2 : 1;
    const short8* Ad_p = Apack + ((size_t)(kindD * BATCH + b) * NT) * 64;
    const short8* At_p = Apack + ((size_t)(kindT * BATCH + b) * NT) * 64;
    const float* c0p = (dir ? c0_1 : c0_2) + b * NPTS;
    const float* h0p = (dir ? h0_w : h0_2) + b * NPTS;

    float sm0 = 0.f, sm1 = 0.f;
    float mn0 = 3.4e38f, mn1 = 3.4e38f;

    const int ct0 = jc * 64;
    #pragma unroll 2
    for (int ct = ct0; ct < ct0 + 64; ++ct) {
        const short8 Ad = Ad_p[(size_t)ct * 64 + l];
        const short8 At = At_p[(size_t)ct * 64 + l];
        const f32x4 c0v = *(const f32x4*)(c0p + ct * 16 + kb * 4);
        const f32x4 h0v = *(const f32x4*)(h0p + ct * 16 + kb * 4);
        // D[m][n] = cloud_m . query_n + bias_m ; col(lane&15)=query, rows=(kb*4+r)=cloud
        f32x4 accd0 = __builtin_amdgcn_mfma_f32_16x16x32_bf16(Ad, Bd0, c0v, 0, 0, 0);
        f32x4 acct0 = __builtin_amdgcn_mfma_f32_16x16x32_bf16(At, Bt0, h0v, 0, 0, 0);
        f32x4 accd1 = __builtin_amdgcn_mfma_f32_16x16x32_bf16(Ad, Bd1, c0v, 0, 0, 0);
        f32x4 acct1 = __builtin_amdgcn_mfma_f32_16x16x32_bf16(At, Bt1, h0v, 0, 0, 0);

        sm0 += (__builtin_amdgcn_exp2f(accd0[0]) + __builtin_amdgcn_exp2f(accd0[1]))
             + (__builtin_amdgcn_exp2f(accd0[2]) + __builtin_amdgcn_exp2f(accd0[3]));
        sm1 += (__builtin_amdgcn_exp2f(accd1[0]) + __builtin_amdgcn_exp2f(accd1[1]))
             + (__builtin_amdgcn_exp2f(accd1[2]) + __builtin_amdgcn_exp2f(accd1[3]));
        mn0 = fminf(mn0, fminf(acct0[0], acct0[1]));   // fuses to v_min3
        mn0 = fminf(mn0, fminf(acct0[2], acct0[3]));
        mn1 = fminf(mn1, fminf(acct1[0], acct1[1]));
        mn1 = fminf(mn1, fminf(acct1[2], acct1[3]));
    }

    // fold the 4 row-quads (lanes l, l^16, l^32, l^48 share a query col)
    sm0 += __shfl_xor(sm0, 16); sm0 += __shfl_xor(sm0, 32);
    sm1 += __shfl_xor(sm1, 16); sm1 += __shfl_xor(sm1, 32);
    mn0 = fminf(mn0, __shfl_xor(mn0, 16)); mn0 = fminf(mn0, __shfl_xor(mn0, 32));
    mn1 = fminf(mn1, __shfl_xor(mn1, 16)); mn1 = fminf(mn1, __shfl_xor(mn1, 32));

    if (l < 16) {
        const int o0 = dirb * NPTS + q0i, o1 = dirb * NPTS + q1i;
        atomicAdd(&dsum[o0], sm0);
        atomicAdd(&dsum[o1], sm1);
        atomicMin(&dmin_u[o0], fenc(mn0));
        atomicMin(&dmin_u[o1], fenc(mn1));
    }
}

// ---- finalize: mask * relu(min + |q|^2 - eps), mean ----
__global__ __launch_bounds__(256) void finalize_kernel(
    const float* __restrict__ pc1, const float* __restrict__ pc2,
    const float* __restrict__ pc1w, const float* __restrict__ dsum,
    const uint32* __restrict__ dmin_u, float* __restrict__ out)
{
    const int gid = blockIdx.x * 256 + threadIdx.x;   // 32768
    const int dirb = gid >> 12, i = gid & (NPTS - 1);
    const int dir = dirb >> 2, b = dirb & 3;
    const size_t qbase = (size_t)b * 3 * NPTS;

    const float* qdens = dir ? pc2 : pc1;
    const float* qdist = dir ? pc2 : pc1w;
    const float ax = qdens[qbase + i], ay = qdens[qbase + NPTS + i], az = qdens[qbase + 2 * NPTS + i];
    const float wx = qdist[qbase + i], wy = qdist[qbase + NPTS + i], wz = qdist[qbase + 2 * NPTS + i];
    const float q0  = -SCONST * (ax * ax + ay * ay + az * az);
    const float qw2 = wx * wx + wy * wy + wz * wz;

    const float dens = dsum[gid] * __builtin_amdgcn_exp2f(q0);
    const float d2   = fdec(dmin_u[gid]) + qw2;
    const float thresh = 0.005f * 2.5f * (float)NPTS;   // 51.2
    float c = (dens > thresh) ? fmaxf(d2 - 0.01f, 0.0f) : 0.0f;

    const int l = threadIdx.x & 63, w = threadIdx.x >> 6;
    #pragma unroll
    for (int off = 32; off > 0; off >>= 1) c += __shfl_down(c, off);
    __shared__ float red[4];
    if (l == 0) red[w] = c;
    __syncthreads();
    if (threadIdx.x == 0)
        atomicAdd(out, (red[0] + red[1] + red[2] + red[3]) *
                       (1.0f / ((float)BATCH * (float)NPTS)));
}

extern "C" void kernel_launch(void* const* d_in, const int* in_sizes, int n_in,
                              void* d_out, int out_size, void* d_ws, size_t ws_size,
                              hipStream_t stream) {
    const float* pc1  = (const float*)d_in[0];
    const float* pc2  = (const float*)d_in[1];
    const float* pc1w = (const float*)d_in[2];
    float* out = (float*)d_out;

    char* ws = (char*)d_ws;
    short8* Apack = (short8*)ws;                              // 3*4*256*64*16 = 3,145,728 B
    float*  c0_1  = (float*)(ws + 3145728);                   // 65536 B each
    float*  c0_2  = (float*)(ws + 3145728 + 65536);
    float*  h0_2  = (float*)(ws + 3145728 + 131072);
    float*  h0_w  = (float*)(ws + 3145728 + 196608);
    float*  dsum  = (float*)(ws + 3145728 + 262144);          // 131072 B
    uint32* dmin  = (uint32*)(ws + 3145728 + 393216);         // 131072 B

    pack_kernel<<<768, 256, 0, stream>>>(pc1, pc2, pc1w, Apack, c0_1, c0_2,
                                         h0_2, h0_w, dsum, dmin, out);
    chamfer_mfma<<<1024, 256, 0, stream>>>(pc1, pc2, pc1w, Apack, c0_1, c0_2,
                                           h0_2, h0_w, dsum, dmin);
    finalize_kernel<<<128, 256, 0, stream>>>(pc1, pc2, pc1w, dsum, dmin, out);
}

// Round 5
// 31.292 us; speedup vs baseline: 1.6054x; 1.6054x over previous
//
#include <hip/hip_runtime.h>

#define BATCH 4
#define NPTS 4096
#define NT32 128             // NPTS/32 cloud tiles
#define SCONST 0.72134752f   // 0.5*log2(e)

typedef __attribute__((ext_vector_type(8))) short short8;
typedef __attribute__((ext_vector_type(16))) float f32x16;
typedef unsigned int uint32;

__device__ __forceinline__ unsigned short bf16rn(float x) {
    uint32 u = __float_as_uint(x);
    uint32 r = (u + 0x7FFFu + ((u >> 16) & 1u)) >> 16;
    return (unsigned short)r;
}
__device__ __forceinline__ float bf16tof(unsigned short h) {
    return __uint_as_float(((uint32)h) << 16);
}
// orderable float<->uint for atomicMin
__device__ __forceinline__ uint32 fenc(float f) {
    uint32 u = __float_as_uint(f);
    return (u & 0x80000000u) ? ~u : (u | 0x80000000u);
}
__device__ __forceinline__ float fdec(uint32 u) {
    return __uint_as_float((u & 0x80000000u) ? (u & 0x7FFFFFFFu) : ~u);
}

// K=16 slot pattern (11 used), A=cloud rows, B=query cols:
//  k0-2 : A=ch{x,y,z}        B=qh{x,y,z}
//  k3-5 : A=cl{x,y,z}        B=qh{x,y,z}
//  k6-8 : A=ch{x,y,z}        B=ql{x,y,z}
//  k9-10: A=bias_h, bias_l   B=1.0, 1.0
// lane-half hi=l>>5 supplies k[hi*8 .. hi*8+7] (same assumption both operands
// -> any true HW k-permutation cancels).
// kinds: 0=dens(pc1,c0=-s|c|^2) 1=dens(pc2,c0) 2=dist(pc2,h0=|c|^2) 3=dist(pc1w,h0)
__global__ __launch_bounds__(256) void pack_kernel(
    const float* __restrict__ pc1, const float* __restrict__ pc2,
    const float* __restrict__ pc1w, short8* __restrict__ Apack,
    float* __restrict__ dsum, uint32* __restrict__ dmin_u, float* __restrict__ out)
{
    const int gid = blockIdx.x * 256 + threadIdx.x;   // 4*4*128*64 = 131072
    if (gid == 0) out[0] = 0.0f;
    if (gid < 2 * BATCH * NPTS) dsum[gid] = 0.0f;
    else if (gid < 4 * BATCH * NPTS) dmin_u[gid - 2 * BATCH * NPTS] = 0xFFFFFFFFu;

    const int kind = gid >> 15;
    const int r    = gid & 32767;
    const int b    = r >> 13;
    const int t    = (r >> 6) & 127;
    const int l    = r & 63;
    const int row  = l & 31, hi = l >> 5;
    const int p    = t * 32 + row;

    const float* src = (kind == 0) ? pc1 : (kind == 3) ? pc1w : pc2;
    const size_t base = (size_t)b * 3 * NPTS;
    const float x = src[base + p], y = src[base + NPTS + p], z = src[base + 2 * NPTS + p];
    const float n2 = x * x + y * y + z * z;
    const float bias = (kind < 2) ? (-SCONST * n2) : n2;

    const unsigned short hx = bf16rn(x), hy = bf16rn(y), hz = bf16rn(z);
    const unsigned short lx = bf16rn(x - bf16tof(hx)),
                         ly = bf16rn(y - bf16tof(hy)),
                         lz = bf16rn(z - bf16tof(hz));
    const unsigned short bh = bf16rn(bias), bl = bf16rn(bias - bf16tof(bh));

    short8 f = (short8)0;
    if (hi == 0) {
        f[0] = (short)hx; f[1] = (short)hy; f[2] = (short)hz;
        f[3] = (short)lx; f[4] = (short)ly; f[5] = (short)lz;
        f[6] = (short)hx; f[7] = (short)hy;
    } else {
        f[0] = (short)hz; f[1] = (short)bh; f[2] = (short)bl;
    }
    Apack[gid] = f;
}

__global__ __launch_bounds__(512, 6) void chamfer_mfma(
    const float* __restrict__ pc1, const float* __restrict__ pc2,
    const float* __restrict__ pc1w, const short8* __restrict__ Apack,
    float* __restrict__ dsum, uint32* __restrict__ dmin_u)
{
    const int blk  = blockIdx.x;
    const int dirb = blk & 7;             // = XCD id (round-robin) -> L2 affinity
    const int dir  = dirb >> 2, b = dirb & 3;
    const int rest = blk >> 3;
    const int qb   = rest & 15;           // 16 query-blocks of 8 tiles (256 queries)
    const int jc   = rest >> 4;           // 8 cloud chunks of 16 tiles
    const int tid  = threadIdx.x, l = tid & 63, w = tid >> 6;
    const int col  = l & 31, hi = l >> 5;

    __shared__ short8 ldsD[16 * 64];      // 16KB density A-chunk
    __shared__ short8 ldsT[16 * 64];      // 16KB distance A-chunk

    // ---- stage cloud chunk (both streams) into LDS, cooperative ----
    const int kindD = dir ? 0 : 1;
    const int kindT = dir ? 3 : 2;
    const short8* AD = Apack + ((size_t)(kindD * BATCH + b) * NT32 + jc * 16) * 64;
    const short8* AT = Apack + ((size_t)(kindT * BATCH + b) * NT32 + jc * 16) * 64;
    #pragma unroll
    for (int t = w; t < 16; t += 8) {
        ldsD[t * 64 + l] = AD[t * 64 + l];
        ldsT[t * 64 + l] = AT[t * 64 + l];
    }

    // ---- build B fragments (query side), scales baked in ----
    const float* qdens = dir ? pc2 : pc1;
    const float* qdist = dir ? pc2 : pc1w;
    const size_t qbase = (size_t)b * 3 * NPTS;
    const int qi = (qb * 8 + w) * 32 + col;

    const float s2 = 2.0f * SCONST;
    float dx = qdens[qbase + qi] * s2, dy = qdens[qbase + NPTS + qi] * s2,
          dz = qdens[qbase + 2 * NPTS + qi] * s2;
    float tx = qdist[qbase + qi] * -2.0f, ty = qdist[qbase + NPTS + qi] * -2.0f,
          tz = qdist[qbase + 2 * NPTS + qi] * -2.0f;
    const unsigned short dhx = bf16rn(dx), dhy = bf16rn(dy), dhz = bf16rn(dz);
    const unsigned short dlx = bf16rn(dx - bf16tof(dhx)), dly = bf16rn(dy - bf16tof(dhy)),
                         dlz = bf16rn(dz - bf16tof(dhz));
    const unsigned short thx = bf16rn(tx), thy = bf16rn(ty), thz = bf16rn(tz);
    const unsigned short tlx = bf16rn(tx - bf16tof(thx)), tly = bf16rn(ty - bf16tof(thy)),
                         tlz = bf16rn(tz - bf16tof(thz));
    const short ONE = (short)0x3F80;      // bf16 1.0

    short8 Bd = (short8)0, Bt = (short8)0;
    if (hi == 0) {
        Bd[0] = (short)dhx; Bd[1] = (short)dhy; Bd[2] = (short)dhz;
        Bd[3] = (short)dhx; Bd[4] = (short)dhy; Bd[5] = (short)dhz;
        Bd[6] = (short)dlx; Bd[7] = (short)dly;
        Bt[0] = (short)thx; Bt[1] = (short)thy; Bt[2] = (short)thz;
        Bt[3] = (short)thx; Bt[4] = (short)thy; Bt[5] = (short)thz;
        Bt[6] = (short)tlx; Bt[7] = (short)tly;
    } else {
        Bd[0] = (short)dlz; Bd[1] = ONE; Bd[2] = ONE;
        Bt[0] = (short)tlz; Bt[1] = ONE; Bt[2] = ONE;
    }
    __syncthreads();

    const f32x16 zc = {0.f,0.f,0.f,0.f,0.f,0.f,0.f,0.f,
                       0.f,0.f,0.f,0.f,0.f,0.f,0.f,0.f};
    float sm = 0.0f;
    float mn = 3.4e38f;

    #pragma unroll 2
    for (int t = 0; t < 16; ++t) {
        // density: D = c.q' + c0 (bias via K-slots), rows=cloud, col=query
        const short8 Ad = ldsD[t * 64 + l];
        f32x16 ad = __builtin_amdgcn_mfma_f32_32x32x16_bf16(Ad, Bd, zc, 0, 0, 0);
        {
            float e0 = __builtin_amdgcn_exp2f(ad[0])  + __builtin_amdgcn_exp2f(ad[1]);
            float e1 = __builtin_amdgcn_exp2f(ad[2])  + __builtin_amdgcn_exp2f(ad[3]);
            float e2 = __builtin_amdgcn_exp2f(ad[4])  + __builtin_amdgcn_exp2f(ad[5]);
            float e3 = __builtin_amdgcn_exp2f(ad[6])  + __builtin_amdgcn_exp2f(ad[7]);
            float e4 = __builtin_amdgcn_exp2f(ad[8])  + __builtin_amdgcn_exp2f(ad[9]);
            float e5 = __builtin_amdgcn_exp2f(ad[10]) + __builtin_amdgcn_exp2f(ad[11]);
            float e6 = __builtin_amdgcn_exp2f(ad[12]) + __builtin_amdgcn_exp2f(ad[13]);
            float e7 = __builtin_amdgcn_exp2f(ad[14]) + __builtin_amdgcn_exp2f(ad[15]);
            sm += ((e0 + e1) + (e2 + e3)) + ((e4 + e5) + (e6 + e7));
        }
        // distance: D = |c|^2 - 2 q.c (bias via K-slots)
        const short8 At2 = ldsT[t * 64 + l];
        f32x16 at = __builtin_amdgcn_mfma_f32_32x32x16_bf16(At2, Bt, zc, 0, 0, 0);
        {
            float m0 = fminf(at[0],  at[1]),  m1 = fminf(at[2],  at[3]);
            float m2 = fminf(at[4],  at[5]),  m3 = fminf(at[6],  at[7]);
            float m4 = fminf(at[8],  at[9]),  m5 = fminf(at[10], at[11]);
            float m6 = fminf(at[12], at[13]), m7 = fminf(at[14], at[15]);
            float ma = fminf(fminf(m0, m1), fminf(m2, m3));
            float mb = fminf(fminf(m4, m5), fminf(m6, m7));
            mn = fminf(mn, fminf(ma, mb));
        }
    }

    // lanes l and l+32 hold the two row-halves of the same query column
    sm += __shfl_xor(sm, 32);
    mn = fminf(mn, __shfl_xor(mn, 32));

    if (l < 32) {
        const int o = dirb * NPTS + qi;
        atomicAdd(&dsum[o], sm);
        atomicMin(&dmin_u[o], fenc(mn));
    }
}

// ---- finalize: mask * relu(min + |q|^2 - eps), mean ----
__global__ __launch_bounds__(256) void finalize_kernel(
    const float* __restrict__ pc1, const float* __restrict__ pc2,
    const float* __restrict__ pc1w, const float* __restrict__ dsum,
    const uint32* __restrict__ dmin_u, float* __restrict__ out)
{
    const int gid = blockIdx.x * 256 + threadIdx.x;   // 32768
    const int dirb = gid >> 12, i = gid & (NPTS - 1);
    const int dir = dirb >> 2, b = dirb & 3;
    const size_t qbase = (size_t)b * 3 * NPTS;

    const float* qdens = dir ? pc2 : pc1;
    const float* qdist = dir ? pc2 : pc1w;
    const float ax = qdens[qbase + i], ay = qdens[qbase + NPTS + i], az = qdens[qbase + 2 * NPTS + i];
    const float wx = qdist[qbase + i], wy = qdist[qbase + NPTS + i], wz = qdist[qbase + 2 * NPTS + i];
    const float q0  = -SCONST * (ax * ax + ay * ay + az * az);
    const float qw2 = wx * wx + wy * wy + wz * wz;

    const float dens = dsum[gid] * __builtin_amdgcn_exp2f(q0);
    const float d2   = fdec(dmin_u[gid]) + qw2;
    const float thresh = 0.005f * 2.5f * (float)NPTS;   // 51.2
    float c = (dens > thresh) ? fmaxf(d2 - 0.01f, 0.0f) : 0.0f;

    const int l = threadIdx.x & 63, w = threadIdx.x >> 6;
    #pragma unroll
    for (int off = 32; off > 0; off >>= 1) c += __shfl_down(c, off);
    __shared__ float red[4];
    if (l == 0) red[w] = c;
    __syncthreads();
    if (threadIdx.x == 0)
        atomicAdd(out, (red[0] + red[1] + red[2] + red[3]) *
                       (1.0f / ((float)BATCH * (float)NPTS)));
}

extern "C" void kernel_launch(void* const* d_in, const int* in_sizes, int n_in,
                              void* d_out, int out_size, void* d_ws, size_t ws_size,
                              hipStream_t stream) {
    const float* pc1  = (const float*)d_in[0];
    const float* pc2  = (const float*)d_in[1];
    const float* pc1w = (const float*)d_in[2];
    float* out = (float*)d_out;

    char* ws = (char*)d_ws;
    short8* Apack = (short8*)ws;                      // 4*4*128*64*16 = 2,097,152 B
    float*  dsum  = (float*)(ws + 2097152);           // 131072 B
    uint32* dmin  = (uint32*)(ws + 2097152 + 131072); // 131072 B

    pack_kernel<<<512, 256, 0, stream>>>(pc1, pc2, pc1w, Apack, dsum, dmin, out);
    chamfer_mfma<<<1024, 512, 0, stream>>>(pc1, pc2, pc1w, Apack, dsum, dmin);
    finalize_kernel<<<128, 256, 0, stream>>>(pc1, pc2, pc1w, dsum, dmin, out);
}

// Round 6
// 25.932 us; speedup vs baseline: 1.9373x; 1.2067x over previous
//
#include <hip/hip_runtime.h>

#define BATCH 4
#define NPTS 4096
#define SCONST 0.72134752f   // 0.5*log2(e)
#define CHUNK_TILES 16       // cloud tiles per block chunk
#define CHUNK_PTS   512      // 32 * CHUNK_TILES

typedef __attribute__((ext_vector_type(8))) short short8;
typedef __attribute__((ext_vector_type(16))) float f32x16;
typedef unsigned int uint32;

__device__ __forceinline__ unsigned short bf16rn(float x) {
    uint32 u = __float_as_uint(x);
    uint32 r = (u + 0x7FFFu + ((u >> 16) & 1u)) >> 16;
    return (unsigned short)r;
}
__device__ __forceinline__ float bf16tof(unsigned short h) {
    return __uint_as_float(((uint32)h) << 16);
}
__device__ __forceinline__ float m3(float a, float b, float c) {
    return fminf(fminf(a, b), c);    // fuses to v_min3_f32
}

// K=16 slot pattern (11 used), A=cloud rows, B=query cols:
//  k0-2: ch.qh   k3-5: cl.qh   k6-8: ch.ql   k9-10: bias_h,bias_l x 1.0
// lane-half hi=l>>5 supplies k[hi*8..hi*8+7]; same assumption on both operands
// so any true HW k-permutation cancels. Bias rides in A; C-operand is zero.
__global__ __launch_bounds__(512, 8) void chamfer_mfma(
    const float* __restrict__ pc1, const float* __restrict__ pc2,
    const float* __restrict__ pc1w,
    float* __restrict__ dsum, float* __restrict__ dmin, float* __restrict__ out)
{
    const int blk  = blockIdx.x;
    const int dirb = blk & 7;             // 8 (dir,b) combos -> XCD L2 affinity
    const int dir  = dirb >> 2, b = dirb & 3;
    const int rest = blk >> 3;
    const int qb   = rest & 15;           // 16 query-blocks of 256 queries
    const int jc   = rest >> 4;           // 8 cloud chunks of 512 points
    const int tid  = threadIdx.x, l = tid & 63, w = tid >> 6;
    const int col  = l & 31, hi = l >> 5;

    if (blk == 0 && tid == 0) out[0] = 0.0f;   // finalize is stream-ordered after

    __shared__ short8 ldsD[CHUNK_TILES * 64];  // 16KB density A-chunk
    __shared__ short8 ldsT[CHUNK_TILES * 64];  // 16KB distance A-chunk

    const size_t cbase = (size_t)b * 3 * NPTS;

    // ---- in-block pack: thread tid packs cloud point (tile=tid>>5,row=tid&31) ----
    {
        const int p  = jc * CHUNK_PTS + tid;
        const int t_ = tid >> 5, r_ = tid & 31;
        const float* srcD = dir ? pc1  : pc2;
        const float* srcT = dir ? pc1w : pc2;
        const float x = srcD[cbase + p], y = srcD[cbase + NPTS + p],
                    z = srcD[cbase + 2 * NPTS + p];
        const float u = srcT[cbase + p], v = srcT[cbase + NPTS + p],
                    q = srcT[cbase + 2 * NPTS + p];
        const float nD = -SCONST * (x * x + y * y + z * z);
        const float nT = u * u + v * v + q * q;

        unsigned short hx = bf16rn(x), hy = bf16rn(y), hz = bf16rn(z);
        unsigned short lx = bf16rn(x - bf16tof(hx)), ly = bf16rn(y - bf16tof(hy)),
                       lz = bf16rn(z - bf16tof(hz));
        unsigned short bh = bf16rn(nD), bl = bf16rn(nD - bf16tof(bh));
        short8 f0 = (short8)0, f1 = (short8)0;
        f0[0]=(short)hx; f0[1]=(short)hy; f0[2]=(short)hz;
        f0[3]=(short)lx; f0[4]=(short)ly; f0[5]=(short)lz;
        f0[6]=(short)hx; f0[7]=(short)hy;
        f1[0]=(short)hz; f1[1]=(short)bh; f1[2]=(short)bl;
        ldsD[t_ * 64 + r_]      = f0;
        ldsD[t_ * 64 + 32 + r_] = f1;

        hx = bf16rn(u); hy = bf16rn(v); hz = bf16rn(q);
        lx = bf16rn(u - bf16tof(hx)); ly = bf16rn(v - bf16tof(hy));
        lz = bf16rn(q - bf16tof(hz));
        bh = bf16rn(nT); bl = bf16rn(nT - bf16tof(bh));
        short8 g0 = (short8)0, g1 = (short8)0;
        g0[0]=(short)hx; g0[1]=(short)hy; g0[2]=(short)hz;
        g0[3]=(short)lx; g0[4]=(short)ly; g0[5]=(short)lz;
        g0[6]=(short)hx; g0[7]=(short)hy;
        g1[0]=(short)hz; g1[1]=(short)bh; g1[2]=(short)bl;
        ldsT[t_ * 64 + r_]      = g0;
        ldsT[t_ * 64 + 32 + r_] = g1;
    }

    // ---- query B-fragments (scales baked in: dens *= 2s, dist *= -2) ----
    const float* qdens = dir ? pc2 : pc1;
    const float* qdist = dir ? pc2 : pc1w;
    const size_t qbase = (size_t)b * 3 * NPTS;
    const int qi = (qb * 8 + w) * 32 + col;

    const float s2 = 2.0f * SCONST;
    float dx = qdens[qbase + qi] * s2, dy = qdens[qbase + NPTS + qi] * s2,
          dz = qdens[qbase + 2 * NPTS + qi] * s2;
    float tx = qdist[qbase + qi] * -2.0f, ty = qdist[qbase + NPTS + qi] * -2.0f,
          tz = qdist[qbase + 2 * NPTS + qi] * -2.0f;
    const unsigned short dhx = bf16rn(dx), dhy = bf16rn(dy), dhz = bf16rn(dz);
    const unsigned short dlx = bf16rn(dx - bf16tof(dhx)), dly = bf16rn(dy - bf16tof(dhy)),
                         dlz = bf16rn(dz - bf16tof(dhz));
    const unsigned short thx = bf16rn(tx), thy = bf16rn(ty), thz = bf16rn(tz);
    const unsigned short tlx = bf16rn(tx - bf16tof(thx)), tly = bf16rn(ty - bf16tof(thy)),
                         tlz = bf16rn(tz - bf16tof(thz));
    const short ONE = (short)0x3F80;     // bf16 1.0

    short8 Bd = (short8)0, Bt = (short8)0;
    if (hi == 0) {
        Bd[0]=(short)dhx; Bd[1]=(short)dhy; Bd[2]=(short)dhz;
        Bd[3]=(short)dhx; Bd[4]=(short)dhy; Bd[5]=(short)dhz;
        Bd[6]=(short)dlx; Bd[7]=(short)dly;
        Bt[0]=(short)thx; Bt[1]=(short)thy; Bt[2]=(short)thz;
        Bt[3]=(short)thx; Bt[4]=(short)thy; Bt[5]=(short)thz;
        Bt[6]=(short)tlx; Bt[7]=(short)tly;
    } else {
        Bd[0]=(short)dlz; Bd[1]=ONE; Bd[2]=ONE;
        Bt[0]=(short)tlz; Bt[1]=ONE; Bt[2]=ONE;
    }
    __syncthreads();

    const f32x16 zc = {0.f,0.f,0.f,0.f,0.f,0.f,0.f,0.f,
                       0.f,0.f,0.f,0.f,0.f,0.f,0.f,0.f};
    float sm = 0.0f;
    float mn = 3.4e38f;

    #pragma unroll 2
    for (int t = 0; t < CHUNK_TILES; ++t) {
        const short8 Ad  = ldsD[t * 64 + l];
        const short8 At2 = ldsT[t * 64 + l];
        // issue both MFMAs before either epilogue (overlap MFMA latency)
        f32x16 ad = __builtin_amdgcn_mfma_f32_32x32x16_bf16(Ad,  Bd, zc, 0, 0, 0);
        f32x16 at = __builtin_amdgcn_mfma_f32_32x32x16_bf16(At2, Bt, zc, 0, 0, 0);

        float e0 = __builtin_amdgcn_exp2f(ad[0])  + __builtin_amdgcn_exp2f(ad[1]);
        float e1 = __builtin_amdgcn_exp2f(ad[2])  + __builtin_amdgcn_exp2f(ad[3]);
        float e2 = __builtin_amdgcn_exp2f(ad[4])  + __builtin_amdgcn_exp2f(ad[5]);
        float e3 = __builtin_amdgcn_exp2f(ad[6])  + __builtin_amdgcn_exp2f(ad[7]);
        float e4 = __builtin_amdgcn_exp2f(ad[8])  + __builtin_amdgcn_exp2f(ad[9]);
        float e5 = __builtin_amdgcn_exp2f(ad[10]) + __builtin_amdgcn_exp2f(ad[11]);
        float e6 = __builtin_amdgcn_exp2f(ad[12]) + __builtin_amdgcn_exp2f(ad[13]);
        float e7 = __builtin_amdgcn_exp2f(ad[14]) + __builtin_amdgcn_exp2f(ad[15]);
        sm += ((e0 + e1) + (e2 + e3)) + ((e4 + e5) + (e6 + e7));

        float n0 = m3(at[0],  at[1],  at[2]);
        float n1 = m3(at[3],  at[4],  at[5]);
        float n2 = m3(at[6],  at[7],  at[8]);
        float n3 = m3(at[9],  at[10], at[11]);
        float n4 = m3(at[12], at[13], at[14]);
        float n5 = m3(n0, n1, n2);
        float n6 = m3(n3, n4, at[15]);
        mn = m3(n5, n6, mn);
    }

    // lanes l and l^32 hold the two row-halves of the same query column
    sm += __shfl_xor(sm, 32);
    mn = fminf(mn, __shfl_xor(mn, 32));

    if (l < 32) {
        const int o = ((jc << 3) | dirb) * NPTS + qi;   // per-chunk slot: no atomics
        dsum[o] = sm;
        dmin[o] = mn;
    }
}

// ---- finalize: combine 8 chunk-partials, mask * relu(min + |q|^2 - eps), mean ----
__global__ __launch_bounds__(512) void finalize_kernel(
    const float* __restrict__ pc1, const float* __restrict__ pc2,
    const float* __restrict__ pc1w, const float* __restrict__ dsum,
    const float* __restrict__ dmin, float* __restrict__ out)
{
    const int gid = blockIdx.x * 512 + threadIdx.x;   // 32768
    const int dirb = gid >> 12, i = gid & (NPTS - 1);
    const int dir = dirb >> 2, b = dirb & 3;
    const size_t qbase = (size_t)b * 3 * NPTS;

    float s = 0.0f, mnv = 3.4e38f;
    #pragma unroll
    for (int jc = 0; jc < 8; ++jc) {
        const int o = ((jc << 3) | dirb) * NPTS + i;
        s += dsum[o];
        mnv = fminf(mnv, dmin[o]);
    }

    const float* qdens = dir ? pc2 : pc1;
    const float* qdist = dir ? pc2 : pc1w;
    const float ax = qdens[qbase + i], ay = qdens[qbase + NPTS + i],
                az = qdens[qbase + 2 * NPTS + i];
    const float wx = qdist[qbase + i], wy = qdist[qbase + NPTS + i],
                wz = qdist[qbase + 2 * NPTS + i];
    const float q0  = -SCONST * (ax * ax + ay * ay + az * az);
    const float qw2 = wx * wx + wy * wy + wz * wz;

    const float dens = s * __builtin_amdgcn_exp2f(q0);
    const float d2   = mnv + qw2;
    const float thresh = 0.005f * 2.5f * (float)NPTS;   // 51.2
    float c = (dens > thresh) ? fmaxf(d2 - 0.01f, 0.0f) : 0.0f;

    const int l = threadIdx.x & 63, w = threadIdx.x >> 6;
    #pragma unroll
    for (int off = 32; off > 0; off >>= 1) c += __shfl_down(c, off);
    __shared__ float red[8];
    if (l == 0) red[w] = c;
    __syncthreads();
    if (threadIdx.x == 0) {
        float tsum = 0.f;
        #pragma unroll
        for (int k = 0; k < 8; ++k) tsum += red[k];
        atomicAdd(out, tsum * (1.0f / ((float)BATCH * (float)NPTS)));
    }
}

extern "C" void kernel_launch(void* const* d_in, const int* in_sizes, int n_in,
                              void* d_out, int out_size, void* d_ws, size_t ws_size,
                              hipStream_t stream) {
    const float* pc1  = (const float*)d_in[0];
    const float* pc2  = (const float*)d_in[1];
    const float* pc1w = (const float*)d_in[2];
    float* out = (float*)d_out;

    char* ws = (char*)d_ws;
    float* dsum = (float*)ws;                 // 8 jc * 8 dirb * 4096 * 4B = 1 MiB
    float* dmin = (float*)(ws + (1 << 20));   // 1 MiB

    chamfer_mfma<<<1024, 512, 0, stream>>>(pc1, pc2, pc1w, dsum, dmin, out);
    finalize_kernel<<<64, 512, 0, stream>>>(pc1, pc2, pc1w, dsum, dmin, out);
}